// Round 2
// baseline (257.845 us; speedup 1.0000x reference)
//
#include <hip/hip_runtime.h>
#include <hip/hip_bf16.h>

#define N_ATOMS 2048
#define F_DIM   64
#define H_DIM   128
#define K_DIM   256
#define KD      (F_DIM * H_DIM)   // 8192

#define BM 16
#define BN 64
#define BK 64

typedef __attribute__((ext_vector_type(8))) short short8;
typedef __attribute__((ext_vector_type(4))) float f32x4;
typedef __attribute__((ext_vector_type(8))) unsigned short ushort8v;

static __device__ __forceinline__ unsigned short f2bf(float x) {
  unsigned int u = __float_as_uint(x);
  u += 0x7fff + ((u >> 16) & 1);           // round-to-nearest-even
  return (unsigned short)(u >> 16);
}

// ---------------------------------------------------------------------------
// Kernel 1: adj_exp[m][f] = sum_n dist_adj[m][n] * dist_exp[m][n][f]
// One block per row m. Streams 512KB of dist_exp per block (1 GiB total).
// ---------------------------------------------------------------------------
__global__ __launch_bounds__(256) void adj_exp_kernel(
    const float* __restrict__ dist_adj,
    const float* __restrict__ dist_exp,
    float* __restrict__ adj_exp) {
  const int m  = blockIdx.x;
  const int t  = threadIdx.x;
  const int f4 = t & 15;    // float4 index over f (covers f = 4*f4 .. 4*f4+3)
  const int ng = t >> 4;    // n-phase 0..15

  const float* __restrict__ arow = dist_adj + (size_t)m * N_ATOMS;
  const float* __restrict__ base = dist_exp + (size_t)m * N_ATOMS * F_DIM + f4 * 4;

  float4 acc = make_float4(0.f, 0.f, 0.f, 0.f);
  #pragma unroll 4
  for (int n = ng; n < N_ATOMS; n += 16) {
    float a  = arow[n];
    float4 v = *(const float4*)(base + (size_t)n * F_DIM);
    acc.x += a * v.x; acc.y += a * v.y; acc.z += a * v.z; acc.w += a * v.w;
  }

  __shared__ float4 red[16][16];   // [ng][f4]
  red[ng][f4] = acc;
  __syncthreads();
  if (t < 16) {
    float4 s = red[0][t];
    #pragma unroll
    for (int g = 1; g < 16; ++g) {
      float4 v = red[g][t];
      s.x += v.x; s.y += v.y; s.z += v.z; s.w += v.w;
    }
    *(float4*)(adj_exp + m * F_DIM + t * 4) = s;
  }
}

// ---------------------------------------------------------------------------
// Kernel 2: Wt[k][f*128+h] = bf16(W[f][h][k])  -- transpose + convert
// W viewed as [KD][K_DIM] row-major; Wt is [K_DIM][KD] bf16.
// ---------------------------------------------------------------------------
__global__ __launch_bounds__(256) void wt_kernel(
    const float* __restrict__ W,
    unsigned short* __restrict__ Wt) {
  const int fh0 = blockIdx.x * 32;
  const int k0  = blockIdx.y * 64;
  const int t   = threadIdx.x;

  __shared__ float tile[32][69];

  {
    const int i  = t >> 4;          // 0..15
    const int k4 = (t & 15) * 4;    // 0..60
    float4 v0 = *(const float4*)(W + (size_t)(fh0 + i)      * K_DIM + k0 + k4);
    float4 v1 = *(const float4*)(W + (size_t)(fh0 + i + 16) * K_DIM + k0 + k4);
    tile[i][k4+0] = v0.x; tile[i][k4+1] = v0.y; tile[i][k4+2] = v0.z; tile[i][k4+3] = v0.w;
    tile[i+16][k4+0] = v1.x; tile[i+16][k4+1] = v1.y; tile[i+16][k4+2] = v1.z; tile[i+16][k4+3] = v1.w;
  }
  __syncthreads();
  {
    const int j  = t >> 2;          // local k 0..63
    const int i8 = (t & 3) * 8;     // fh group 0,8,16,24
    ushort8v v;
    v[0] = f2bf(tile[i8+0][j]); v[1] = f2bf(tile[i8+1][j]);
    v[2] = f2bf(tile[i8+2][j]); v[3] = f2bf(tile[i8+3][j]);
    v[4] = f2bf(tile[i8+4][j]); v[5] = f2bf(tile[i8+5][j]);
    v[6] = f2bf(tile[i8+6][j]); v[7] = f2bf(tile[i8+7][j]);
    *(ushort8v*)(Wt + (size_t)(k0 + j) * KD + fh0 + i8) = v;
  }
}

// ---------------------------------------------------------------------------
// Kernel 3: feat = U @ Wv, U[n, f*128+h] = adj_exp[n,f]*emb[n,h] (on the fly)
// then out = softplus(feat) + bias (f32 output).
// BM=16, BN=64, BK=64; 4 waves: wave w owns cols [w*16, w*16+16).
// ---------------------------------------------------------------------------
__global__ __launch_bounds__(256) void bilinear_kernel(
    const float* __restrict__ adj_exp,         // [2048][64]
    const float* __restrict__ emb,             // [2048][128]
    const unsigned short* __restrict__ Wt,     // [256][8192] bf16
    const float* __restrict__ bias,            // [256]
    float* __restrict__ out) {                 // [2048][256] f32
  const int m0 = blockIdx.x * BM;
  const int c0 = blockIdx.y * BN;
  const int t  = threadIdx.x;
  const int w  = t >> 6;
  const int l  = t & 63;
  const int lr = l & 15;
  const int lg = l >> 4;

  __shared__ unsigned short Alds[BM][72];   // [m][k] bf16 (pad 64->72)
  __shared__ unsigned short Blds[BN][72];   // [col][k] bf16 (B^T layout)

  const int am = t >> 4;          // 0..15 (A row)
  const int aj = (t & 15) * 4;    // 0..60 (A k-chunk of 4)
  const int bc = t >> 2;          // 0..63 (B col)
  const int bj = (t & 3) * 8;     // 0,8,16,24 (B k-chunk of 8; +32 for 2nd half)

  f32x4 acc = {0.f, 0.f, 0.f, 0.f};

  for (int kk = 0; kk < KD; kk += BK) {
    const int f  = kk >> 7;
    const int h0 = kk & 127;
    __syncthreads();
    // --- stage A: 16x64 products ---
    {
      float  a = adj_exp[(m0 + am) * F_DIM + f];
      float4 e = *(const float4*)(emb + (size_t)(m0 + am) * H_DIM + h0 + aj);
      ushort4 p;
      p.x = f2bf(a * e.x); p.y = f2bf(a * e.y);
      p.z = f2bf(a * e.z); p.w = f2bf(a * e.w);
      *(ushort4*)&Alds[am][aj] = p;
    }
    // --- stage B: 64 cols x 64 k from Wt (already transposed) ---
    {
      const unsigned short* wrow = Wt + (size_t)(c0 + bc) * KD + kk + bj;
      *(uint4*)&Blds[bc][bj]      = *(const uint4*)(wrow);
      *(uint4*)&Blds[bc][bj + 32] = *(const uint4*)(wrow + 32);
    }
    __syncthreads();
    // --- MFMA: 2 steps of K=32 ---
    short8 a0 = *(const short8*)&Alds[lr][lg * 8];
    short8 a1 = *(const short8*)&Alds[lr][32 + lg * 8];
    short8 b0 = *(const short8*)&Blds[w * 16 + lr][lg * 8];
    short8 b1 = *(const short8*)&Blds[w * 16 + lr][32 + lg * 8];
    acc = __builtin_amdgcn_mfma_f32_16x16x32_bf16(a0, b0, acc, 0, 0, 0);
    acc = __builtin_amdgcn_mfma_f32_16x16x32_bf16(a1, b1, acc, 0, 0, 0);
  }

  // --- epilogue: softplus + bias, write f32 ---
  const int col = c0 + w * 16 + lr;
  const float b = bias[col];
  #pragma unroll
  for (int r = 0; r < 4; ++r) {
    const int row = m0 + lg * 4 + r;
    float x  = acc[r];
    float sp = (x > 20.f) ? x : ((x < -20.f) ? __expf(x) : log1pf(__expf(x)));
    out[(size_t)row * K_DIM + col] = sp + b;
  }
}

// ---------------------------------------------------------------------------
extern "C" void kernel_launch(void* const* d_in, const int* in_sizes, int n_in,
                              void* d_out, int out_size, void* d_ws, size_t ws_size,
                              hipStream_t stream) {
  const float* dist_adj   = (const float*)d_in[0];   // [2048][2048]
  const float* dist_exp   = (const float*)d_in[1];   // [2048][2048][64]
  const float* atom_emb   = (const float*)d_in[2];   // [2048][128]
  const float* bilinear_w = (const float*)d_in[3];   // [64][128][256]
  const float* bilinear_b = (const float*)d_in[4];   // [256]
  float* out = (float*)d_out;                        // f32 [2048][256]

  float* adj_exp = (float*)d_ws;                                   // 512 KB
  unsigned short* Wt =
      (unsigned short*)((char*)d_ws + (size_t)N_ATOMS * F_DIM * sizeof(float)); // 4 MB

  hipLaunchKernelGGL(adj_exp_kernel, dim3(N_ATOMS), dim3(256), 0, stream,
                     dist_adj, dist_exp, adj_exp);
  hipLaunchKernelGGL(wt_kernel, dim3(KD / 32, K_DIM / 64), dim3(256), 0, stream,
                     bilinear_w, Wt);
  hipLaunchKernelGGL(bilinear_kernel, dim3(N_ATOMS / BM, K_DIM / BN), dim3(256), 0, stream,
                     adj_exp, atom_emb, Wt, bilinear_b, out);
}

// Round 4
// 237.658 us; speedup vs baseline: 1.0849x; 1.0849x over previous
//
#include <hip/hip_runtime.h>
#include <hip/hip_bf16.h>

#define N_ATOMS 2048
#define F_DIM   64
#define H_DIM   128
#define K_DIM   256
#define KD      8192
#define BM 32
#define BN 64
#define BK 128
#define NT (KD / BK)   // 64 K-steps

typedef __attribute__((ext_vector_type(8))) short short8;
typedef __attribute__((ext_vector_type(4))) float f32x4;
typedef __attribute__((ext_vector_type(8))) unsigned short ushort8v;

static __device__ __forceinline__ unsigned short f2bf(float x) {
  unsigned int u = __float_as_uint(x);
  u += 0x7fff + ((u >> 16) & 1);           // round-to-nearest-even
  return (unsigned short)(u >> 16);
}

// ---------------------------------------------------------------------------
// Kernel 1: adj_exp[m][f] = sum_n dist_adj[m][n] * dist_exp[m][n][f]
// Streams 1 GiB coalesced; at HBM roofline.
// ---------------------------------------------------------------------------
__global__ __launch_bounds__(256) void adj_exp_kernel(
    const float* __restrict__ dist_adj,
    const float* __restrict__ dist_exp,
    float* __restrict__ adj_exp) {
  const int m  = blockIdx.x;
  const int t  = threadIdx.x;
  const int f4 = t & 15;
  const int ng = t >> 4;

  const float* __restrict__ arow = dist_adj + (size_t)m * N_ATOMS;
  const float* __restrict__ base = dist_exp + (size_t)m * N_ATOMS * F_DIM + f4 * 4;

  float4 acc = make_float4(0.f, 0.f, 0.f, 0.f);
  #pragma unroll 4
  for (int n = ng; n < N_ATOMS; n += 16) {
    float a  = arow[n];
    float4 v = *(const float4*)(base + (size_t)n * F_DIM);
    acc.x += a * v.x; acc.y += a * v.y; acc.z += a * v.z; acc.w += a * v.w;
  }

  __shared__ float4 red[16][16];
  red[ng][f4] = acc;
  __syncthreads();
  if (t < 16) {
    float4 s = red[0][t];
    #pragma unroll
    for (int g = 1; g < 16; ++g) {
      float4 v = red[g][t];
      s.x += v.x; s.y += v.y; s.z += v.z; s.w += v.w;
    }
    *(float4*)(adj_exp + m * F_DIM + t * 4) = s;
  }
}

// ---------------------------------------------------------------------------
// Kernel 2: Wt tiled+swizzled bf16 image.
// Logical B element (c, fh) = W[fh][c].  Tile (cb,kb): c in [cb*64,+64),
// fh in [kb*128,+128). 16KB tile image byte layout:
//   off(cc,kk) = cc*256 + ((kk*2) ^ ((cc&7)<<4))
// so bilinear can global_load_lds it linearly and ds_read conflict-free.
// ---------------------------------------------------------------------------
__global__ __launch_bounds__(256) void wt_kernel(
    const float* __restrict__ W,
    unsigned short* __restrict__ Wt) {
  const int kb = blockIdx.x;    // 0..63
  const int cb = blockIdx.y;    // 0..3
  const int t  = threadIdx.x;

  __shared__ float tile[128][68];   // [fh][c], pad 68

  {
    const int r0 = t >> 4;          // 0..15
    const int c4 = (t & 15) * 4;    // 0..60
    #pragma unroll
    for (int i = 0; i < 8; ++i) {
      const int r = i * 16 + r0;
      float4 v = *(const float4*)(W + (size_t)(kb * 128 + r) * K_DIM + cb * 64 + c4);
      tile[r][c4 + 0] = v.x; tile[r][c4 + 1] = v.y;
      tile[r][c4 + 2] = v.z; tile[r][c4 + 3] = v.w;
    }
  }
  __syncthreads();
  {
    char* outb = (char*)Wt + (size_t)((cb << 6) | kb) * 16384;
    #pragma unroll
    for (int j = 0; j < 4; ++j) {
      const int o   = t * 64 + j * 16;           // byte offset in tile image
      const int cc  = o >> 8;
      const int r0b = (o & 255) ^ ((cc & 7) << 4);
      const int kk0 = r0b >> 1;
      ushort8v v;
      #pragma unroll
      for (int e = 0; e < 8; ++e) v[e] = f2bf(tile[kk0 + e][cc]);
      *(ushort8v*)(outb + o) = v;
    }
  }
}

// ---------------------------------------------------------------------------
// Kernel 3: feat = U @ B, U[n, f*128+h] = adj_exp[n,f]*emb[n,h] built from
// registers; B staged via global_load_lds from pre-swizzled Wt tiles;
// 2-phase double-buffer with counted vmcnt; softplus+bias epilogue (f32).
// 4 waves; wave w owns cols [w*16,+16) and both 16-row m-tiles (acc x2).
// ---------------------------------------------------------------------------
__global__ __launch_bounds__(256) void bilinear_kernel(
    const float* __restrict__ adj_exp,         // [2048][64]
    const float* __restrict__ emb,             // [2048][128]
    const unsigned short* __restrict__ Wt,     // tiled swizzled bf16
    const float* __restrict__ bias,            // [256]
    float* __restrict__ out) {                 // [2048][256] f32
  // bijective XCD swizzle (nwg=256 divisible by 8)
  const int b  = blockIdx.x;
  const int wg = (b & 7) * 32 + (b >> 3);
  const int mb = wg & 63;
  const int cb = wg >> 6;
  const int m0 = mb * BM;
  const int c0 = cb * BN;

  const int t  = threadIdx.x;
  const int w  = t >> 6;
  const int l  = t & 63;
  const int lr = l & 15;
  const int lg = l >> 4;

  __shared__ __align__(16) unsigned short Bl[2][8192];       // 16KB swizzled tiles
  __shared__ __align__(16) unsigned short Al[2][BM][136];    // [m][k] bf16, pad 136
  __shared__ float adjT[F_DIM][BM];                          // transposed adj block

  // ---- staging helpers ----
  const char* wt_base = (const char*)Wt;
  #define STAGE_B(buf, step)                                                      \
    {                                                                             \
      const char* src = wt_base + (size_t)((cb << 6) | (step)) * 16384;           \
      char* dstb = (char*)&Bl[(buf)][0];                                          \
      _Pragma("unroll")                                                           \
      for (int i = 0; i < 4; ++i) {                                               \
        const int chunk = i * 4 + w;                                              \
        __builtin_amdgcn_global_load_lds(                                         \
            (const __attribute__((address_space(1))) unsigned int*)(src + chunk * 1024 + l * 16), \
            (__attribute__((address_space(3))) unsigned int*)(dstb + chunk * 1024), \
            16, 0, 0);                                                            \
      }                                                                           \
    }

  const int arow = t >> 3;          // 0..31 (A-staging row)
  const int hc   = (t & 7) * 16;    // h-chunk base
  #define STAGE_A(buf, step)                                                      \
    {                                                                             \
      const float s = adjT[(step)][arow];                                         \
      ushort8v lo, hi;                                                            \
      _Pragma("unroll")                                                           \
      for (int i = 0; i < 8; ++i) {                                               \
        lo[i] = f2bf(s * er[i]);                                                  \
        hi[i] = f2bf(s * er[8 + i]);                                              \
      }                                                                           \
      *(ushort8v*)&Al[(buf)][arow][hc]     = lo;                                  \
      *(ushort8v*)&Al[(buf)][arow][hc + 8] = hi;                                  \
    }

  // ---- prologue ----
  STAGE_B(0, 0);          // start B DMA early (overlaps preloads)

  float er[16];
  {
    const float* ep = emb + (size_t)(m0 + arow) * H_DIM + hc;
    #pragma unroll
    for (int i = 0; i < 4; ++i) {
      float4 e = *(const float4*)(ep + i * 4);
      er[i * 4 + 0] = e.x; er[i * 4 + 1] = e.y;
      er[i * 4 + 2] = e.z; er[i * 4 + 3] = e.w;
    }
  }
  {
    const int r  = t & 31;
    const int f0 = (t >> 5) * 8;
    float4 a0 = *(const float4*)(adj_exp + (size_t)(m0 + r) * F_DIM + f0);
    float4 a1 = *(const float4*)(adj_exp + (size_t)(m0 + r) * F_DIM + f0 + 4);
    adjT[f0 + 0][r] = a0.x; adjT[f0 + 1][r] = a0.y;
    adjT[f0 + 2][r] = a0.z; adjT[f0 + 3][r] = a0.w;
    adjT[f0 + 4][r] = a1.x; adjT[f0 + 5][r] = a1.y;
    adjT[f0 + 6][r] = a1.z; adjT[f0 + 7][r] = a1.w;
  }
  __syncthreads();        // adjT visible to ALL waves before first STAGE_A (r3 bug)

  STAGE_A(0, 0);
  __syncthreads();        // full drain: buf0 A + B ready

  f32x4 acc0 = {0.f, 0.f, 0.f, 0.f};
  f32x4 acc1 = {0.f, 0.f, 0.f, 0.f};
  const int ccol = w * 16 + lr;
  const int bswz = (lr & 7) << 4;

  int cur = 0;
  #pragma unroll 1
  for (int ts = 0; ts < NT; ++ts) {
    const int nxt = cur ^ 1;
    if (ts + 1 < NT) {
      STAGE_B(nxt, ts + 1);
      STAGE_A(nxt, ts + 1);
      asm volatile("s_waitcnt vmcnt(4)" ::: "memory");   // buf[cur] B done
    } else {
      asm volatile("s_waitcnt vmcnt(0)" ::: "memory");
    }
    asm volatile("s_waitcnt lgkmcnt(0)" ::: "memory");   // A[nxt] writes done
    __builtin_amdgcn_s_barrier();
    asm volatile("" ::: "memory");

    // compute on buf[cur]
    const char* Bbase = (const char*)&Bl[cur][0];
    #pragma unroll
    for (int ks = 0; ks < 4; ++ks) {
      const int boff = ccol * 256 + ((ks * 64 + lg * 16) ^ bswz);
      short8 bf = *(const short8*)(Bbase + boff);
      short8 a0 = *(const short8*)&Al[cur][lr][ks * 32 + lg * 8];
      short8 a1 = *(const short8*)&Al[cur][16 + lr][ks * 32 + lg * 8];
      acc0 = __builtin_amdgcn_mfma_f32_16x16x32_bf16(a0, bf, acc0, 0, 0, 0);
      acc1 = __builtin_amdgcn_mfma_f32_16x16x32_bf16(a1, bf, acc1, 0, 0, 0);
    }

    asm volatile("s_waitcnt lgkmcnt(0)" ::: "memory");   // reads of cur done
    __builtin_amdgcn_s_barrier();
    asm volatile("" ::: "memory");
    cur = nxt;
  }
  #undef STAGE_A
  #undef STAGE_B

  // ---- epilogue: softplus + bias, f32 out ----
  const int col = c0 + ccol;
  const float bb = bias[col];
  #pragma unroll
  for (int r = 0; r < 4; ++r) {
    const int row0 = m0 + lg * 4 + r;
    float x0  = acc0[r];
    float sp0 = (x0 > 20.f) ? x0 : ((x0 < -20.f) ? __expf(x0) : log1pf(__expf(x0)));
    out[(size_t)row0 * K_DIM + col] = sp0 + bb;
    const int row1 = row0 + 16;
    float x1  = acc1[r];
    float sp1 = (x1 > 20.f) ? x1 : ((x1 < -20.f) ? __expf(x1) : log1pf(__expf(x1)));
    out[(size_t)row1 * K_DIM + col] = sp1 + bb;
  }
}

// ---------------------------------------------------------------------------
extern "C" void kernel_launch(void* const* d_in, const int* in_sizes, int n_in,
                              void* d_out, int out_size, void* d_ws, size_t ws_size,
                              hipStream_t stream) {
  const float* dist_adj   = (const float*)d_in[0];   // [2048][2048]
  const float* dist_exp   = (const float*)d_in[1];   // [2048][2048][64]
  const float* atom_emb   = (const float*)d_in[2];   // [2048][128]
  const float* bilinear_w = (const float*)d_in[3];   // [64][128][256]
  const float* bilinear_b = (const float*)d_in[4];   // [256]
  float* out = (float*)d_out;                        // f32 [2048][256]

  float* adj_exp = (float*)d_ws;                                   // 512 KB
  unsigned short* Wt =
      (unsigned short*)((char*)d_ws + (size_t)N_ATOMS * F_DIM * sizeof(float)); // 4 MB

  hipLaunchKernelGGL(adj_exp_kernel, dim3(N_ATOMS), dim3(256), 0, stream,
                     dist_adj, dist_exp, adj_exp);
  hipLaunchKernelGGL(wt_kernel, dim3(NT, K_DIM / BN), dim3(256), 0, stream,
                     bilinear_w, Wt);
  hipLaunchKernelGGL(bilinear_kernel, dim3((N_ATOMS / BM) * (K_DIM / BN)), dim3(256), 0, stream,
                     adj_exp, atom_emb, Wt, bilinear_b, out);
}

// Round 5
// 225.493 us; speedup vs baseline: 1.1435x; 1.0539x over previous
//
#include <hip/hip_runtime.h>
#include <hip/hip_bf16.h>

#define N_ATOMS 2048
#define F_DIM   64
#define H_DIM   128
#define K_DIM   256
#define KD      8192
#define BM 32
#define BN 64
#define BK 128
#define NT (KD / BK)   // 64 K-steps

typedef __attribute__((ext_vector_type(8))) short short8;
typedef __attribute__((ext_vector_type(4))) float f32x4;
typedef __attribute__((ext_vector_type(8))) unsigned short ushort8v;

static __device__ __forceinline__ unsigned short f2bf(float x) {
  unsigned int u = __float_as_uint(x);
  u += 0x7fff + ((u >> 16) & 1);           // round-to-nearest-even
  return (unsigned short)(u >> 16);
}

// ---------------------------------------------------------------------------
// Fat kernel: blocks 0..511 transpose+convert W into swizzled tiles (wt path);
// blocks 512..2559 compute adj_exp rows (streaming path). The wt work rides
// under the memory-bound stream instead of serializing.
// Shared LDS: 17408 B (wt tile [64][68] f32); adj path aliases 12.3 KB of it.
// ---------------------------------------------------------------------------
__global__ __launch_bounds__(256) void fused_prep_kernel(
    const float* __restrict__ dist_adj,
    const float* __restrict__ dist_exp,
    const float* __restrict__ W,
    float* __restrict__ adj_exp,
    unsigned short* __restrict__ Wt) {
  __shared__ __align__(16) char smem[17408];
  const int t = threadIdx.x;

  if (blockIdx.x < 512) {
    // ---- wt path: 64 fh-rows x 64 cols per block ----
    const int q    = blockIdx.x;
    const int cb   = q >> 7;          // 0..3
    const int kb   = (q >> 1) & 63;   // 0..63
    const int half = q & 1;           // 0..1
    float (*tile)[68] = (float(*)[68])smem;

    {
      const int r0 = t >> 4;          // 0..15
      const int c4 = (t & 15) * 4;    // 0..60
      #pragma unroll
      for (int i = 0; i < 4; ++i) {
        const int r = i * 16 + r0;
        f32x4 v = *(const f32x4*)(W + (size_t)(kb * 128 + half * 64 + r) * K_DIM + cb * 64 + c4);
        tile[r][c4 + 0] = v[0]; tile[r][c4 + 1] = v[1];
        tile[r][c4 + 2] = v[2]; tile[r][c4 + 3] = v[3];
      }
    }
    __syncthreads();
    {
      char* outb = (char*)Wt + (size_t)((cb << 6) | kb) * 16384;
      #pragma unroll
      for (int j = 0; j < 2; ++j) {
        const int lin  = t * 32 + j * 16;          // 0..8191
        const int cc   = lin >> 7;                 // 0..63
        const int w128 = lin & 127;
        const int k0   = (w128 ^ ((cc & 7) << 4)) >> 1;   // local fh row, mult of 8
        ushort8v v;
        #pragma unroll
        for (int e = 0; e < 8; ++e) v[e] = f2bf(tile[k0 + e][cc]);
        *(ushort8v*)(outb + cc * 256 + half * 128 + w128) = v;
      }
    }
  } else {
    // ---- adj path: adj_exp[m][f] = sum_n dist_adj[m][n]*dist_exp[m][n][f] ----
    const int m  = blockIdx.x - 512;
    const int f4 = t & 15;
    const int ng = t >> 4;

    float* arowl = (float*)smem;                       // 8 KB
    f32x4* red   = (f32x4*)(smem + 8192);              // 4 KB [16][16]

    {
      const f32x4* src = (const f32x4*)(dist_adj + (size_t)m * N_ATOMS);
      f32x4* dst = (f32x4*)arowl;
      #pragma unroll
      for (int i = 0; i < 2; ++i) {
        const int idx = i * 256 + t;                   // 512 float4 total
        dst[idx] = __builtin_nontemporal_load(src + idx);
      }
    }
    __syncthreads();

    const float* __restrict__ base = dist_exp + (size_t)m * N_ATOMS * F_DIM + f4 * 4;
    f32x4 acc = {0.f, 0.f, 0.f, 0.f};
    #pragma unroll 4
    for (int n = ng; n < N_ATOMS; n += 16) {
      float a  = arowl[n];
      f32x4 v = __builtin_nontemporal_load((const f32x4*)(base + (size_t)n * F_DIM));
      acc += a * v;
    }

    red[ng * 16 + f4] = acc;
    __syncthreads();
    if (t < 16) {
      f32x4 s = red[t];
      #pragma unroll
      for (int g = 1; g < 16; ++g) s += red[g * 16 + t];
      *(f32x4*)(adj_exp + m * F_DIM + t * 4) = s;
    }
  }
}

// ---------------------------------------------------------------------------
// Bilinear GEMM: feat[m,c] = sum_f a[m,f] * (E . W_f)[m,c].
// E (emb rows) lives in registers for the whole kernel (never changes across
// K-steps); per step: t_acc = E_frag x B (8 MFMA), then facc += a[m,f] * t_acc
// in f32 VALU. B staged via global_load_lds from pre-swizzled Wt tiles,
// double-buffered with counted vmcnt (structure identical to verified r4).
// ---------------------------------------------------------------------------
__global__ __launch_bounds__(256) void bilinear_kernel(
    const float* __restrict__ adj_exp,         // [2048][64]
    const float* __restrict__ emb,             // [2048][128]
    const unsigned short* __restrict__ Wt,     // tiled swizzled bf16
    const float* __restrict__ bias,            // [256]
    float* __restrict__ out) {                 // [2048][256] f32
  // bijective XCD swizzle (nwg=256 divisible by 8)
  const int b  = blockIdx.x;
  const int wg = (b & 7) * 32 + (b >> 3);
  const int mb = wg & 63;
  const int cb = wg >> 6;
  const int m0 = mb * BM;
  const int c0 = cb * BN;

  const int t  = threadIdx.x;
  const int w  = t >> 6;
  const int l  = t & 63;
  const int lr = l & 15;
  const int lg = l >> 4;

  __shared__ __align__(16) unsigned short Bl[2][8192];   // 16KB swizzled tiles
  __shared__ __align__(16) float adjT[F_DIM][BM];        // [f][m] 8KB

  const char* wt_base = (const char*)Wt;
  #define STAGE_B(buf, step)                                                      \
    {                                                                             \
      const char* src = wt_base + (size_t)((cb << 6) | (step)) * 16384;           \
      char* dstb = (char*)&Bl[(buf)][0];                                          \
      _Pragma("unroll")                                                           \
      for (int i = 0; i < 4; ++i) {                                               \
        const int chunk = i * 4 + w;                                              \
        __builtin_amdgcn_global_load_lds(                                         \
            (const __attribute__((address_space(1))) unsigned int*)(src + chunk * 1024 + l * 16), \
            (__attribute__((address_space(3))) unsigned int*)(dstb + chunk * 1024), \
            16, 0, 0);                                                            \
      }                                                                           \
    }

  // ---- prologue: start buf0 DMA, then fill registers + adjT ----
  STAGE_B(0, 0);

  // E fragments in registers: rows (m0+lr) and (m0+16+lr), k = ks*32+lg*8 .. +8
  short8 Ef0[4], Ef1[4];
  #pragma unroll
  for (int ks = 0; ks < 4; ++ks) {
    const float* p0 = emb + (size_t)(m0 + lr) * H_DIM + ks * 32 + lg * 8;
    const float* p1 = emb + (size_t)(m0 + 16 + lr) * H_DIM + ks * 32 + lg * 8;
    f32x4 u0 = *(const f32x4*)p0, u1 = *(const f32x4*)(p0 + 4);
    f32x4 v0 = *(const f32x4*)p1, v1 = *(const f32x4*)(p1 + 4);
    short8 e0, e1;
    #pragma unroll
    for (int i = 0; i < 4; ++i) {
      e0[i]     = (short)f2bf(u0[i]); e0[4 + i] = (short)f2bf(u1[i]);
      e1[i]     = (short)f2bf(v0[i]); e1[4 + i] = (short)f2bf(v1[i]);
    }
    Ef0[ks] = e0; Ef1[ks] = e1;
  }
  {
    const int r  = t & 31;
    const int f0 = (t >> 5) * 8;
    f32x4 a0 = *(const f32x4*)(adj_exp + (size_t)(m0 + r) * F_DIM + f0);
    f32x4 a1 = *(const f32x4*)(adj_exp + (size_t)(m0 + r) * F_DIM + f0 + 4);
    adjT[f0 + 0][r] = a0[0]; adjT[f0 + 1][r] = a0[1];
    adjT[f0 + 2][r] = a0[2]; adjT[f0 + 3][r] = a0[3];
    adjT[f0 + 4][r] = a1[0]; adjT[f0 + 5][r] = a1[1];
    adjT[f0 + 6][r] = a1[2]; adjT[f0 + 7][r] = a1[3];
  }
  __syncthreads();   // adjT visible; also drains buf0 DMA (compiler vmcnt(0))

  f32x4 facc0 = {0.f, 0.f, 0.f, 0.f};
  f32x4 facc1 = {0.f, 0.f, 0.f, 0.f};
  const int ccol = w * 16 + lr;
  const int bswz = (lr & 7) << 4;

  int cur = 0;
  #pragma unroll 1
  for (int ts = 0; ts < NT; ++ts) {
    const int nxt = cur ^ 1;
    if (ts + 1 < NT) {
      STAGE_B(nxt, ts + 1);
      asm volatile("s_waitcnt vmcnt(4)" ::: "memory");   // buf[cur] B done
    } else {
      asm volatile("s_waitcnt vmcnt(0)" ::: "memory");
    }
    __builtin_amdgcn_s_barrier();
    asm volatile("" ::: "memory");

    // per-step scales a[m, f=ts] (broadcast reads, conflict-free)
    f32x4 a0 = *(const f32x4*)&adjT[ts][lg * 4];
    f32x4 a1 = *(const f32x4*)&adjT[ts][16 + lg * 4];

    const char* Bbase = (const char*)&Bl[cur][0];
    f32x4 t0 = {0.f, 0.f, 0.f, 0.f};
    f32x4 t1 = {0.f, 0.f, 0.f, 0.f};
    #pragma unroll
    for (int ks = 0; ks < 4; ++ks) {
      const int boff = ccol * 256 + ((ks * 64 + lg * 16) ^ bswz);
      short8 bf = *(const short8*)(Bbase + boff);
      t0 = __builtin_amdgcn_mfma_f32_16x16x32_bf16(Ef0[ks], bf, t0, 0, 0, 0);
      t1 = __builtin_amdgcn_mfma_f32_16x16x32_bf16(Ef1[ks], bf, t1, 0, 0, 0);
    }
    facc0 += a0 * t0;
    facc1 += a1 * t1;

    asm volatile("s_waitcnt lgkmcnt(0)" ::: "memory");   // reads of cur done
    __builtin_amdgcn_s_barrier();
    asm volatile("" ::: "memory");
    cur = nxt;
  }
  #undef STAGE_B

  // ---- epilogue: softplus + bias, f32 out ----
  const int col = c0 + ccol;
  const float bb = bias[col];
  #pragma unroll
  for (int r = 0; r < 4; ++r) {
    const int row0 = m0 + lg * 4 + r;
    float x0  = facc0[r];
    float sp0 = (x0 > 20.f) ? x0 : ((x0 < -20.f) ? __expf(x0) : log1pf(__expf(x0)));
    out[(size_t)row0 * K_DIM + col] = sp0 + bb;
    const int row1 = row0 + 16;
    float x1  = facc1[r];
    float sp1 = (x1 > 20.f) ? x1 : ((x1 < -20.f) ? __expf(x1) : log1pf(__expf(x1)));
    out[(size_t)row1 * K_DIM + col] = sp1 + bb;
  }
}

// ---------------------------------------------------------------------------
extern "C" void kernel_launch(void* const* d_in, const int* in_sizes, int n_in,
                              void* d_out, int out_size, void* d_ws, size_t ws_size,
                              hipStream_t stream) {
  const float* dist_adj   = (const float*)d_in[0];   // [2048][2048]
  const float* dist_exp   = (const float*)d_in[1];   // [2048][2048][64]
  const float* atom_emb   = (const float*)d_in[2];   // [2048][128]
  const float* bilinear_w = (const float*)d_in[3];   // [64][128][256]
  const float* bilinear_b = (const float*)d_in[4];   // [256]
  float* out = (float*)d_out;                        // f32 [2048][256]

  float* adj_exp = (float*)d_ws;                                   // 512 KB
  unsigned short* Wt =
      (unsigned short*)((char*)d_ws + (size_t)N_ATOMS * F_DIM * sizeof(float)); // 4 MB

  hipLaunchKernelGGL(fused_prep_kernel, dim3(512 + N_ATOMS), dim3(256), 0, stream,
                     dist_adj, dist_exp, bilinear_w, adj_exp, Wt);
  hipLaunchKernelGGL(bilinear_kernel, dim3((N_ATOMS / BM) * (K_DIM / BN)), dim3(256), 0, stream,
                     adj_exp, atom_emb, Wt, bilinear_b, out);
}

// Round 6
// 213.670 us; speedup vs baseline: 1.2067x; 1.0553x over previous
//
#include <hip/hip_runtime.h>
#include <hip/hip_bf16.h>

#define N_ATOMS 2048
#define F_DIM   64
#define H_DIM   128
#define K_DIM   256
#define KD      8192
#define BM 64
#define BN 32
#define BK 128
#define NT (KD / BK)   // 64 K-steps

typedef __attribute__((ext_vector_type(8))) short short8;
typedef __attribute__((ext_vector_type(4))) float f32x4;
typedef __attribute__((ext_vector_type(8))) unsigned short ushort8v;

static __device__ __forceinline__ unsigned short f2bf(float x) {
  unsigned int u = __float_as_uint(x);
  u += 0x7fff + ((u >> 16) & 1);           // round-to-nearest-even
  return (unsigned short)(u >> 16);
}

// ---------------------------------------------------------------------------
// Fat kernel: blocks 0..511 transpose+convert W into swizzled 8KB tiles;
// blocks 512..2559 compute adj_exp rows (1 GiB stream, at HBM roofline).
// ---------------------------------------------------------------------------
__global__ __launch_bounds__(256) void fused_prep_kernel(
    const float* __restrict__ dist_adj,
    const float* __restrict__ dist_exp,
    const float* __restrict__ W,
    float* __restrict__ adj_exp,
    unsigned short* __restrict__ Wt) {
  __shared__ __align__(16) char smem[17408];
  const int t = threadIdx.x;

  if (blockIdx.x < 512) {
    // ---- wt path: 64 fh-rows x 64 cols per block ----
    const int q    = blockIdx.x;
    const int cb   = q >> 7;          // 0..3  (64-col group)
    const int kb   = (q >> 1) & 63;   // 0..63 (K-step)
    const int half = q & 1;           // fh half (64 rows)
    float (*tile)[68] = (float(*)[68])smem;

    {
      const int r0 = t >> 4;          // 0..15
      const int c4 = (t & 15) * 4;    // 0..60
      #pragma unroll
      for (int i = 0; i < 4; ++i) {
        const int r = i * 16 + r0;
        f32x4 v = *(const f32x4*)(W + (size_t)(kb * 128 + half * 64 + r) * K_DIM + cb * 64 + c4);
        tile[r][c4 + 0] = v[0]; tile[r][c4 + 1] = v[1];
        tile[r][c4 + 2] = v[2]; tile[r][c4 + 3] = v[3];
      }
    }
    __syncthreads();
    {
      char* outb = (char*)Wt;
      #pragma unroll
      for (int j = 0; j < 2; ++j) {
        const int lin  = t * 32 + j * 16;          // 0..8191
        const int cc   = lin >> 7;                 // 0..63 (col in 64-group)
        const int w128 = lin & 127;
        const int k0   = (w128 ^ ((cc & 7) << 4)) >> 1;   // local fh row (mult of 8)
        ushort8v v;
        #pragma unroll
        for (int e = 0; e < 8; ++e) v[e] = f2bf(tile[k0 + e][cc]);
        // 8KB tile id = (global 32-col group)*64 + kb
        const size_t tb = (size_t)(((cb * 2 + (cc >> 5)) << 6) | kb) * 8192;
        *(ushort8v*)(outb + tb + (cc & 31) * 256 + half * 128 + w128) = v;
      }
    }
  } else {
    // ---- adj path ----
    const int m  = blockIdx.x - 512;
    const int f4 = t & 15;
    const int ng = t >> 4;

    float* arowl = (float*)smem;                       // 8 KB
    f32x4* red   = (f32x4*)(smem + 8192);              // 4 KB

    {
      const f32x4* src = (const f32x4*)(dist_adj + (size_t)m * N_ATOMS);
      f32x4* dst = (f32x4*)arowl;
      #pragma unroll
      for (int i = 0; i < 2; ++i) {
        const int idx = i * 256 + t;
        dst[idx] = __builtin_nontemporal_load(src + idx);
      }
    }
    __syncthreads();

    const float* __restrict__ base = dist_exp + (size_t)m * N_ATOMS * F_DIM + f4 * 4;
    f32x4 acc = {0.f, 0.f, 0.f, 0.f};
    #pragma unroll 4
    for (int n = ng; n < N_ATOMS; n += 16) {
      float a  = arowl[n];
      f32x4 v = __builtin_nontemporal_load((const f32x4*)(base + (size_t)n * F_DIM));
      acc += a * v;
    }

    red[ng * 16 + f4] = acc;
    __syncthreads();
    if (t < 16) {
      f32x4 s = red[t];
      #pragma unroll
      for (int g = 1; g < 16; ++g) s += red[g * 16 + t];
      *(f32x4*)(adj_exp + m * F_DIM + t * 4) = s;
    }
  }
}

// ---------------------------------------------------------------------------
// Bilinear: feat[m,c] = sum_f a[m,f] * (E . W_f)[m,c].  BM=64 x BN=32.
// E in registers (never changes); a from 16KB adjT LDS table; B staged via
// global_load_lds from pre-swizzled 8KB Wt tiles, 4-buffer depth-2 pipeline,
// ONE barrier + counted vmcnt per K-step.
// Wave w: col-group cg=w&1 (16 cols), row-block rb=(w>>1)*32 (2 sub-frags).
// ---------------------------------------------------------------------------
__global__ __launch_bounds__(256) void bilinear_kernel(
    const float* __restrict__ adj_exp,         // [2048][64]
    const float* __restrict__ emb,             // [2048][128]
    const unsigned short* __restrict__ Wt,     // tiled swizzled bf16
    const float* __restrict__ bias,            // [256]
    float* __restrict__ out) {                 // [2048][256] f32
  // bijective XCD swizzle (256 % 8 == 0); each XCD gets one 512KB col panel
  const int b   = blockIdx.x;
  const int wg  = (b & 7) * 32 + (b >> 3);
  const int cbt = wg >> 5;       // 0..7 (32-col panel)
  const int mb  = wg & 31;       // 0..31
  const int m0  = mb * BM;
  const int c0  = cbt * BN;

  const int t  = threadIdx.x;
  const int w  = t >> 6;
  const int l  = t & 63;
  const int lr = l & 15;
  const int lg = l >> 4;
  const int cg = w & 1;
  const int rb = (w >> 1) * 32;

  __shared__ __align__(16) unsigned short Bl[4][4096];   // 4 x 8KB tiles
  __shared__ __align__(16) float adjT[F_DIM][BM];        // [f][m] 16KB

  const char* wt_base = (const char*)Wt;
  #define STAGE_B(buf, step)                                                      \
    {                                                                             \
      const char* src = wt_base + (size_t)((cbt << 6) | (step)) * 8192;           \
      char* dstb = (char*)&Bl[(buf)][0];                                          \
      _Pragma("unroll")                                                           \
      for (int i = 0; i < 2; ++i) {                                               \
        const int chunk = w * 2 + i;                                              \
        __builtin_amdgcn_global_load_lds(                                         \
            (const __attribute__((address_space(1))) unsigned int*)(src + chunk * 1024 + l * 16), \
            (__attribute__((address_space(3))) unsigned int*)(dstb + chunk * 1024), \
            16, 0, 0);                                                            \
      }                                                                           \
    }

  // ---- prologue: start first two DMAs, then fill registers + adjT ----
  STAGE_B(0, 0);
  STAGE_B(1, 1);

  short8 Ef0[4], Ef1[4];   // rows m0+rb+lr and m0+rb+16+lr
  {
    const float* p0 = emb + (size_t)(m0 + rb + lr) * H_DIM;
    const float* p1 = emb + (size_t)(m0 + rb + 16 + lr) * H_DIM;
    #pragma unroll
    for (int ks = 0; ks < 4; ++ks) {
      f32x4 u0 = *(const f32x4*)(p0 + ks * 32 + lg * 8);
      f32x4 u1 = *(const f32x4*)(p0 + ks * 32 + lg * 8 + 4);
      f32x4 v0 = *(const f32x4*)(p1 + ks * 32 + lg * 8);
      f32x4 v1 = *(const f32x4*)(p1 + ks * 32 + lg * 8 + 4);
      short8 e0, e1;
      #pragma unroll
      for (int i = 0; i < 4; ++i) {
        e0[i] = (short)f2bf(u0[i]); e0[4 + i] = (short)f2bf(u1[i]);
        e1[i] = (short)f2bf(v0[i]); e1[4 + i] = (short)f2bf(v1[i]);
      }
      Ef0[ks] = e0; Ef1[ks] = e1;
    }
  }
  {
    const int r  = t & 63;
    const int fb = (t >> 6) * 16;
    #pragma unroll
    for (int i = 0; i < 4; ++i) {
      f32x4 a = *(const f32x4*)(adj_exp + (size_t)(m0 + r) * F_DIM + fb + i * 4);
      adjT[fb + i * 4 + 0][r] = a[0]; adjT[fb + i * 4 + 1][r] = a[1];
      adjT[fb + i * 4 + 2][r] = a[2]; adjT[fb + i * 4 + 3][r] = a[3];
    }
  }
  __syncthreads();   // adjT visible to all; also drains stage(0),(1)

  f32x4 facc0 = {0.f, 0.f, 0.f, 0.f};
  f32x4 facc1 = {0.f, 0.f, 0.f, 0.f};
  const int c_loc = cg * 16 + lr;
  const int bswz  = (lr & 7) << 4;

  #pragma unroll 1
  for (int ts = 0; ts < NT; ++ts) {
    if (ts + 2 < NT) {
      STAGE_B((ts + 2) & 3, ts + 2);
      asm volatile("s_waitcnt vmcnt(4)" ::: "memory");   // my step-ts loads done
    } else if (ts + 2 == NT) {
      asm volatile("s_waitcnt vmcnt(2)" ::: "memory");
    } else {
      asm volatile("s_waitcnt vmcnt(0)" ::: "memory");
    }
    __builtin_amdgcn_s_barrier();                        // everyone's loads done
    asm volatile("" ::: "memory");

    const char* Bbase = (const char*)&Bl[ts & 3][0];
    f32x4 t0 = {0.f, 0.f, 0.f, 0.f};
    f32x4 t1 = {0.f, 0.f, 0.f, 0.f};
    #pragma unroll
    for (int ks = 0; ks < 4; ++ks) {
      const int boff = c_loc * 256 + ((ks * 64 + lg * 16) ^ bswz);
      short8 bf = *(const short8*)(Bbase + boff);
      t0 = __builtin_amdgcn_mfma_f32_16x16x32_bf16(Ef0[ks], bf, t0, 0, 0, 0);
      t1 = __builtin_amdgcn_mfma_f32_16x16x32_bf16(Ef1[ks], bf, t1, 0, 0, 0);
    }
    f32x4 a0 = *(const f32x4*)&adjT[ts][rb + lg * 4];
    f32x4 a1 = *(const f32x4*)&adjT[ts][rb + 16 + lg * 4];
    facc0 += a0 * t0;
    facc1 += a1 * t1;
  }
  #undef STAGE_B

  // ---- epilogue: softplus + bias, f32 out ----
  const int col = c0 + c_loc;
  const float bb = bias[col];
  #pragma unroll
  for (int r = 0; r < 4; ++r) {
    const int row0 = m0 + rb + lg * 4 + r;
    float x0  = facc0[r];
    float sp0 = (x0 > 20.f) ? x0 : ((x0 < -20.f) ? __expf(x0) : log1pf(__expf(x0)));
    out[(size_t)row0 * K_DIM + col] = sp0 + bb;
    const int row1 = row0 + 16;
    float x1  = facc1[r];
    float sp1 = (x1 > 20.f) ? x1 : ((x1 < -20.f) ? __expf(x1) : log1pf(__expf(x1)));
    out[(size_t)row1 * K_DIM + col] = sp1 + bb;
  }
}

// ---------------------------------------------------------------------------
extern "C" void kernel_launch(void* const* d_in, const int* in_sizes, int n_in,
                              void* d_out, int out_size, void* d_ws, size_t ws_size,
                              hipStream_t stream) {
  const float* dist_adj   = (const float*)d_in[0];   // [2048][2048]
  const float* dist_exp   = (const float*)d_in[1];   // [2048][2048][64]
  const float* atom_emb   = (const float*)d_in[2];   // [2048][128]
  const float* bilinear_w = (const float*)d_in[3];   // [64][128][256]
  const float* bilinear_b = (const float*)d_in[4];   // [256]
  float* out = (float*)d_out;                        // f32 [2048][256]

  float* adj_exp = (float*)d_ws;                                   // 512 KB
  unsigned short* Wt =
      (unsigned short*)((char*)d_ws + (size_t)N_ATOMS * F_DIM * sizeof(float)); // 4 MB

  hipLaunchKernelGGL(fused_prep_kernel, dim3(512 + N_ATOMS), dim3(256), 0, stream,
                     dist_adj, dist_exp, bilinear_w, adj_exp, Wt);
  hipLaunchKernelGGL(bilinear_kernel, dim3((N_ATOMS / BM) * (K_DIM / BN)), dim3(256), 0, stream,
                     adj_exp, atom_emb, Wt, bilinear_b, out);
}